// Round 2
// baseline (551.483 us; speedup 1.0000x reference)
//
#include <hip/hip_runtime.h>

#define NEG 0.01f

// ---------------- CSR build ----------------

__global__ void count_kernel(const int* __restrict__ dst, int* __restrict__ cnt, int E) {
  int e = blockIdx.x * blockDim.x + threadIdx.x;
  if (e < E) atomicAdd(&cnt[dst[e]], 1);
}

// level-1: per-256-block exclusive scan, block totals to bsum
__global__ __launch_bounds__(256) void scan_up(const int* __restrict__ cnt,
                                               int* __restrict__ row_ptr,
                                               int* __restrict__ bsum, int n) {
  __shared__ int s[256];
  int t = threadIdx.x;
  int i = blockIdx.x * 256 + t;
  int v = (i < n) ? cnt[i] : 0;
  s[t] = v;
  __syncthreads();
  for (int off = 1; off < 256; off <<= 1) {
    int u = (t >= off) ? s[t - off] : 0;
    __syncthreads();
    s[t] += u;
    __syncthreads();
  }
  if (i < n) row_ptr[i] = s[t] - v;  // block-local exclusive
  if (t == 255) bsum[blockIdx.x] = s[255];
}

// level-2: single block scans B block-sums in place (exclusive)
__global__ __launch_bounds__(256) void scan_mid(int* __restrict__ bsum, int B) {
  __shared__ int s[256];
  int t = threadIdx.x;
  int chunk = (B + 255) >> 8;
  int st = t * chunk, en = min(st + chunk, B);
  int sum = 0;
  for (int i = st; i < en; ++i) sum += bsum[i];
  s[t] = sum;
  __syncthreads();
  for (int off = 1; off < 256; off <<= 1) {
    int u = (t >= off) ? s[t - off] : 0;
    __syncthreads();
    s[t] += u;
    __syncthreads();
  }
  int run = s[t] - sum;
  for (int i = st; i < en; ++i) {
    int c = bsum[i];
    bsum[i] = run;
    run += c;
  }
}

// level-3: add block offsets; emit nxt, dinv, row_ptr[n]
__global__ __launch_bounds__(256) void scan_down(int* __restrict__ row_ptr,
                                                 const int* __restrict__ bsum,
                                                 int* __restrict__ nxt,
                                                 const int* __restrict__ cnt,
                                                 float* __restrict__ dinv, int n, int E) {
  int i = blockIdx.x * 256 + threadIdx.x;
  if (i < n) {
    int r = row_ptr[i] + bsum[blockIdx.x];
    row_ptr[i] = r;
    nxt[i] = r;
    dinv[i] = rsqrtf((float)cnt[i] + 1.0f);  // +1 self-loop
  }
  if (i == 0) row_ptr[n] = E;
}

__global__ void fill_kernel(const int* __restrict__ src, const int* __restrict__ dst,
                            const float* __restrict__ dinv, int* __restrict__ nxt,
                            int* __restrict__ col, float* __restrict__ wcsr, int E) {
  int e = blockIdx.x * blockDim.x + threadIdx.x;
  if (e < E) {
    int d = dst[e], s = src[e];
    int pos = atomicAdd(&nxt[d], 1);
    col[pos] = s;
    wcsr[pos] = dinv[s] * dinv[d];
  }
}

// ---------------- Aggregation (CSR, one wave per node, 64 feats/lane) ----------------

// ax[i,:] = sum_{s in N(i)} w * x[s,:] + dinv_i^2 * x[i,:]
__global__ __launch_bounds__(256) void aggx_kernel(const float* __restrict__ x,
                                                   const float* __restrict__ dinv,
                                                   const int* __restrict__ row_ptr,
                                                   const int* __restrict__ col,
                                                   const float* __restrict__ wcsr,
                                                   float* __restrict__ ax, int n) {
  int lane = threadIdx.x & 63;
  int i = blockIdx.x * 4 + (threadIdx.x >> 6);
  if (i >= n) return;
  float di = dinv[i];
  float acc = x[(size_t)i * 64 + lane] * (di * di);
  int e0 = row_ptr[i], e1 = row_ptr[i + 1];
  for (int e = e0; e < e1; ++e)
    acc = fmaf(x[(size_t)col[e] * 64 + lane], wcsr[e], acc);
  ax[(size_t)i * 64 + lane] = acc;
}

// out[i,:] = x[i,:] + b2[:] + sum w * h2[s,:] + dinv_i^2 * h2[i,:]
__global__ __launch_bounds__(256) void agg2_kernel(const float* __restrict__ h2,
                                                   const float* __restrict__ dinv,
                                                   const int* __restrict__ row_ptr,
                                                   const int* __restrict__ col,
                                                   const float* __restrict__ wcsr,
                                                   const float* __restrict__ b,
                                                   const float* __restrict__ x,
                                                   float* __restrict__ out, int n) {
  int lane = threadIdx.x & 63;
  int i = blockIdx.x * 4 + (threadIdx.x >> 6);
  if (i >= n) return;
  float di = dinv[i];
  float acc = h2[(size_t)i * 64 + lane] * (di * di);
  int e0 = row_ptr[i], e1 = row_ptr[i + 1];
  for (int e = e0; e < e1; ++e)
    acc = fmaf(h2[(size_t)col[e] * 64 + lane], wcsr[e], acc);
  out[(size_t)i * 64 + lane] = x[(size_t)i * 64 + lane] + acc + b[lane];
}

// ---------------- GEMMs (f32 vector ALU; register-tiled 4x4) ----------------

// y1[n,128] = leaky(ax[n,64] @ W1[64,128] + b1)
// tile: 32 nodes x 128 j; thread: 4 nodes x 4 j
__global__ __launch_bounds__(256) void gemm1_kernel(const float* __restrict__ ax,
                                                    const float* __restrict__ W,
                                                    const float* __restrict__ b,
                                                    float* __restrict__ y1, int n) {
  __shared__ float sW[64 * 128];     // 32 KB
  __shared__ float sxT[64][36];      // k-major, padded; 9.2 KB
  int t = threadIdx.x;
  for (int idx = t * 4; idx < 64 * 128; idx += 256 * 4)
    *(float4*)&sW[idx] = *(const float4*)&W[idx];
  int node0 = blockIdx.x * 32;
  // stage x tile transposed: 32 nodes x 64 k
  for (int f = t * 4; f < 32 * 64; f += 256 * 4) {
    int nl = f >> 6, k4 = f & 63;
    int node = node0 + nl;
    float4 v = (node < n) ? *(const float4*)&ax[(size_t)node * 64 + k4]
                          : make_float4(0.f, 0.f, 0.f, 0.f);
    sxT[k4 + 0][nl] = v.x;
    sxT[k4 + 1][nl] = v.y;
    sxT[k4 + 2][nl] = v.z;
    sxT[k4 + 3][nl] = v.w;
  }
  __syncthreads();
  int tx = t & 31, ty = t >> 5;      // j0 = 4*tx, nl0 = 4*ty
  int j0 = tx * 4, nl0 = ty * 4;
  float acc[4][4] = {};
#pragma unroll
  for (int k = 0; k < 64; ++k) {
    float4 w4 = *(const float4*)&sW[k * 128 + j0];
    float4 a4 = *(const float4*)&sxT[k][nl0];
    float a[4] = {a4.x, a4.y, a4.z, a4.w};
    float w[4] = {w4.x, w4.y, w4.z, w4.w};
#pragma unroll
    for (int u = 0; u < 4; ++u)
#pragma unroll
      for (int v = 0; v < 4; ++v) acc[u][v] = fmaf(a[u], w[v], acc[u][v]);
  }
  float4 bb = *(const float4*)&b[j0];
  float bv[4] = {bb.x, bb.y, bb.z, bb.w};
#pragma unroll
  for (int u = 0; u < 4; ++u) {
    int node = node0 + nl0 + u;
    if (node < n) {
      float4 o;
      float* op = &o.x;
#pragma unroll
      for (int v = 0; v < 4; ++v) {
        float s = acc[u][v] + bv[v];
        op[v] = (s >= 0.f) ? s : NEG * s;
      }
      *(float4*)&y1[(size_t)node * 128 + j0] = o;
    }
  }
}

// h2[n,64] = y1[n,128] @ W2[128,64]
// tile: 64 nodes x 64 j; thread: 4 nodes x 4 j
__global__ __launch_bounds__(256) void gemm2_kernel(const float* __restrict__ y1,
                                                    const float* __restrict__ W,
                                                    float* __restrict__ h2, int n) {
  __shared__ float sW[128 * 64];     // 32 KB
  __shared__ float syT[128][68];     // k-major, padded; 34.8 KB
  int t = threadIdx.x;
  for (int idx = t * 4; idx < 128 * 64; idx += 256 * 4)
    *(float4*)&sW[idx] = *(const float4*)&W[idx];
  int node0 = blockIdx.x * 64;
  for (int f = t * 4; f < 64 * 128; f += 256 * 4) {
    int nl = f >> 7, k4 = f & 127;
    int node = node0 + nl;
    float4 v = (node < n) ? *(const float4*)&y1[(size_t)node * 128 + k4]
                          : make_float4(0.f, 0.f, 0.f, 0.f);
    syT[k4 + 0][nl] = v.x;
    syT[k4 + 1][nl] = v.y;
    syT[k4 + 2][nl] = v.z;
    syT[k4 + 3][nl] = v.w;
  }
  __syncthreads();
  int tx = t & 15, ty = t >> 4;      // j0 = 4*tx (64 j), nl0 = 4*ty (64 nodes)
  int j0 = tx * 4, nl0 = ty * 4;
  float acc[4][4] = {};
#pragma unroll 8
  for (int k = 0; k < 128; ++k) {
    float4 w4 = *(const float4*)&sW[k * 64 + j0];
    float4 a4 = *(const float4*)&syT[k][nl0];
    float a[4] = {a4.x, a4.y, a4.z, a4.w};
    float w[4] = {w4.x, w4.y, w4.z, w4.w};
#pragma unroll
    for (int u = 0; u < 4; ++u)
#pragma unroll
      for (int v = 0; v < 4; ++v) acc[u][v] = fmaf(a[u], w[v], acc[u][v]);
  }
#pragma unroll
  for (int u = 0; u < 4; ++u) {
    int node = node0 + nl0 + u;
    if (node < n) {
      float4 o = make_float4(acc[u][0], acc[u][1], acc[u][2], acc[u][3]);
      *(float4*)&h2[(size_t)node * 64 + j0] = o;
    }
  }
}

// ---------------- launch ----------------

extern "C" void kernel_launch(void* const* d_in, const int* in_sizes, int n_in,
                              void* d_out, int out_size, void* d_ws, size_t ws_size,
                              hipStream_t stream) {
  const int n = in_sizes[0] / 64;   // 50000
  const int E = in_sizes[5] / 2;    // 800000

  const float* x  = (const float*)d_in[0];
  const float* W1 = (const float*)d_in[1];
  const float* b1 = (const float*)d_in[2];
  const float* W2 = (const float*)d_in[3];
  const float* b2 = (const float*)d_in[4];
  const int* edge = (const int*)d_in[5];
  const int* esrc = edge;       // edge_index[0]
  const int* edst = edge + E;   // edge_index[1]

  char* ws = (char*)d_ws;
  size_t o = 0;
  auto take = [&](size_t bytes) -> void* {
    void* p = ws + o;
    o += (bytes + 255) & ~(size_t)255;
    return p;
  };
  const int NB = (n + 255) / 256;   // scan blocks (196)
  int*   cnt     = (int*)take((size_t)n * 4);
  int*   row_ptr = (int*)take((size_t)(n + 1) * 4);
  int*   nxt     = (int*)take((size_t)n * 4);
  float* dinv    = (float*)take((size_t)n * 4);
  int*   bsum    = (int*)take((size_t)NB * 4);
  int*   col     = (int*)take((size_t)E * 4);
  float* wcsr    = (float*)take((size_t)E * 4);
  float* ax      = (float*)take((size_t)n * 64 * 4);
  float* y1      = (float*)take((size_t)n * 128 * 4);
  float* h2      = ax;  // ax dead after gemm1; reuse

  hipMemsetAsync(cnt, 0, (size_t)n * 4, stream);

  int eb = (E + 255) / 256;
  count_kernel<<<eb, 256, 0, stream>>>(edst, cnt, E);
  scan_up<<<NB, 256, 0, stream>>>(cnt, row_ptr, bsum, n);
  scan_mid<<<1, 256, 0, stream>>>(bsum, NB);
  scan_down<<<NB, 256, 0, stream>>>(row_ptr, bsum, nxt, cnt, dinv, n, E);
  fill_kernel<<<eb, 256, 0, stream>>>(esrc, edst, dinv, nxt, col, wcsr, E);

  aggx_kernel<<<(n + 3) / 4, 256, 0, stream>>>(x, dinv, row_ptr, col, wcsr, ax, n);
  gemm1_kernel<<<(n + 31) / 32, 256, 0, stream>>>(ax, W1, b1, y1, n);
  gemm2_kernel<<<(n + 63) / 64, 256, 0, stream>>>(y1, W2, h2, n);
  agg2_kernel<<<(n + 3) / 4, 256, 0, stream>>>(h2, dinv, row_ptr, col, wcsr, b2, x,
                                               (float*)d_out, n);
}

// Round 3
// 356.373 us; speedup vs baseline: 1.5475x; 1.5475x over previous
//
#include <hip/hip_runtime.h>

#define NEG 0.01f

// ---------------- CSR build ----------------

__global__ void count_kernel(const int* __restrict__ dst, int* __restrict__ cnt, int E) {
  int e = blockIdx.x * blockDim.x + threadIdx.x;
  if (e < E) atomicAdd(&cnt[dst[e]], 1);
}

// level-1: per-256-block exclusive scan, block totals to bsum
__global__ __launch_bounds__(256) void scan_up(const int* __restrict__ cnt,
                                               int* __restrict__ row_ptr,
                                               int* __restrict__ bsum, int n) {
  __shared__ int s[256];
  int t = threadIdx.x;
  int i = blockIdx.x * 256 + t;
  int v = (i < n) ? cnt[i] : 0;
  s[t] = v;
  __syncthreads();
  for (int off = 1; off < 256; off <<= 1) {
    int u = (t >= off) ? s[t - off] : 0;
    __syncthreads();
    s[t] += u;
    __syncthreads();
  }
  if (i < n) row_ptr[i] = s[t] - v;  // block-local exclusive
  if (t == 255) bsum[blockIdx.x] = s[255];
}

// level-2: single block scans B block-sums in place (exclusive)
__global__ __launch_bounds__(256) void scan_mid(int* __restrict__ bsum, int B) {
  __shared__ int s[256];
  int t = threadIdx.x;
  int chunk = (B + 255) >> 8;
  int st = t * chunk, en = min(st + chunk, B);
  int sum = 0;
  for (int i = st; i < en; ++i) sum += bsum[i];
  s[t] = sum;
  __syncthreads();
  for (int off = 1; off < 256; off <<= 1) {
    int u = (t >= off) ? s[t - off] : 0;
    __syncthreads();
    s[t] += u;
    __syncthreads();
  }
  int run = s[t] - sum;
  for (int i = st; i < en; ++i) {
    int c = bsum[i];
    bsum[i] = run;
    run += c;
  }
}

// level-3: add block offsets; emit nxt, dinv, row_ptr[n]
__global__ __launch_bounds__(256) void scan_down(int* __restrict__ row_ptr,
                                                 const int* __restrict__ bsum,
                                                 int* __restrict__ nxt,
                                                 const int* __restrict__ cnt,
                                                 float* __restrict__ dinv, int n, int E) {
  int i = blockIdx.x * 256 + threadIdx.x;
  if (i < n) {
    int r = row_ptr[i] + bsum[blockIdx.x];
    row_ptr[i] = r;
    nxt[i] = r;
    dinv[i] = rsqrtf((float)cnt[i] + 1.0f);  // +1 self-loop
  }
  if (i == 0) row_ptr[n] = E;
}

__global__ void fill_kernel(const int* __restrict__ src, const int* __restrict__ dst,
                            const float* __restrict__ dinv, int* __restrict__ nxt,
                            int* __restrict__ col, float* __restrict__ wcsr, int E) {
  int e = blockIdx.x * blockDim.x + threadIdx.x;
  if (e < E) {
    int d = dst[e], s = src[e];
    int pos = atomicAdd(&nxt[d], 1);
    col[pos] = s;
    wcsr[pos] = dinv[s] * dinv[d];
  }
}

// ---------------- Aggregation (CSR, one wave per node, 64 feats/lane) ----------------

// ax[i,:] = sum_{s in N(i)} w * x[s,:] + dinv_i^2 * x[i,:]
__global__ __launch_bounds__(256) void aggx_kernel(const float* __restrict__ x,
                                                   const float* __restrict__ dinv,
                                                   const int* __restrict__ row_ptr,
                                                   const int* __restrict__ col,
                                                   const float* __restrict__ wcsr,
                                                   float* __restrict__ ax, int n) {
  int lane = threadIdx.x & 63;
  int i = blockIdx.x * 4 + (threadIdx.x >> 6);
  if (i >= n) return;
  float di = dinv[i];
  float acc = x[(size_t)i * 64 + lane] * (di * di);
  int e0 = row_ptr[i], e1 = row_ptr[i + 1];
  for (int e = e0; e < e1; ++e)
    acc = fmaf(x[(size_t)col[e] * 64 + lane], wcsr[e], acc);
  ax[(size_t)i * 64 + lane] = acc;
}

// out[i,:] = x[i,:] + b2[:] + sum w * h2[s,:] + dinv_i^2 * h2[i,:]
__global__ __launch_bounds__(256) void agg2_kernel(const float* __restrict__ h2,
                                                   const float* __restrict__ dinv,
                                                   const int* __restrict__ row_ptr,
                                                   const int* __restrict__ col,
                                                   const float* __restrict__ wcsr,
                                                   const float* __restrict__ b,
                                                   const float* __restrict__ x,
                                                   float* __restrict__ out, int n) {
  int lane = threadIdx.x & 63;
  int i = blockIdx.x * 4 + (threadIdx.x >> 6);
  if (i >= n) return;
  float di = dinv[i];
  float acc = h2[(size_t)i * 64 + lane] * (di * di);
  int e0 = row_ptr[i], e1 = row_ptr[i + 1];
  for (int e = e0; e < e1; ++e)
    acc = fmaf(h2[(size_t)col[e] * 64 + lane], wcsr[e], acc);
  out[(size_t)i * 64 + lane] = x[(size_t)i * 64 + lane] + acc + b[lane];
}

// ---------------- GEMMs (f32 vector ALU; R1-proven structure, no spills) ----------------

// y1[n,128] = leaky(ax[n,64] @ W1[64,128] + b1); 2 nodes/iter, 1 out/thread
__global__ __launch_bounds__(256) void gemm1_kernel(const float* __restrict__ ax,
                                                    const float* __restrict__ W,
                                                    const float* __restrict__ b,
                                                    float* __restrict__ y1, int n) {
  __shared__ float sW[64 * 128];   // 32 KB
  __shared__ float sx[2][64];
  int t = threadIdx.x;
  for (int idx = t * 4; idx < 64 * 128; idx += 256 * 4)
    *(float4*)&sW[idx] = *(const float4*)&W[idx];
  float bj = b[t & 127];
  int npairs = (n + 1) >> 1;
  for (int p = blockIdx.x; p < npairs; p += gridDim.x) {
    int node0 = p << 1;
    __syncthreads();  // sW ready (first iter); sx reuse safe (later iters)
    if (t < 128) {
      int node = node0 + (t >> 6);
      int k = t & 63;
      sx[t >> 6][k] = (node < n) ? ax[(size_t)node * 64 + k] : 0.f;
    }
    __syncthreads();
    int local = t >> 7;        // 0..1
    int j = t & 127;
    int node = node0 + local;
    if (node < n) {
      float acc = 0.f;
#pragma unroll 16
      for (int k = 0; k < 64; ++k) acc = fmaf(sx[local][k], sW[k * 128 + j], acc);
      float s = acc + bj;
      y1[(size_t)node * 128 + j] = (s >= 0.f) ? s : NEG * s;
    }
  }
}

// h2[n,64] = y1[n,128] @ W2[128,64]; 4 nodes/iter, 1 out/thread
__global__ __launch_bounds__(256) void gemm2_kernel(const float* __restrict__ y,
                                                    const float* __restrict__ W,
                                                    float* __restrict__ h2, int n) {
  __shared__ float sW[128 * 64];   // 32 KB
  __shared__ float sy[4][128];
  int t = threadIdx.x;
  for (int idx = t * 4; idx < 128 * 64; idx += 256 * 4)
    *(float4*)&sW[idx] = *(const float4*)&W[idx];
  int nquads = (n + 3) >> 2;
  for (int q = blockIdx.x; q < nquads; q += gridDim.x) {
    int node0 = q << 2;
    __syncthreads();
    for (int f = t; f < 512; f += 256) {
      int node = node0 + (f >> 7);
      int k = f & 127;
      sy[f >> 7][k] = (node < n) ? y[(size_t)node * 128 + k] : 0.f;
    }
    __syncthreads();
    int local = t >> 6;        // 0..3
    int j = t & 63;
    int node = node0 + local;
    if (node < n) {
      float acc = 0.f;
#pragma unroll 16
      for (int k = 0; k < 128; ++k) acc = fmaf(sy[local][k], sW[k * 64 + j], acc);
      h2[(size_t)node * 64 + j] = acc;
    }
  }
}

// ---------------- launch ----------------

extern "C" void kernel_launch(void* const* d_in, const int* in_sizes, int n_in,
                              void* d_out, int out_size, void* d_ws, size_t ws_size,
                              hipStream_t stream) {
  const int n = in_sizes[0] / 64;   // 50000
  const int E = in_sizes[5] / 2;    // 800000

  const float* x  = (const float*)d_in[0];
  const float* W1 = (const float*)d_in[1];
  const float* b1 = (const float*)d_in[2];
  const float* W2 = (const float*)d_in[3];
  const float* b2 = (const float*)d_in[4];
  const int* edge = (const int*)d_in[5];
  const int* esrc = edge;       // edge_index[0]
  const int* edst = edge + E;   // edge_index[1]

  char* ws = (char*)d_ws;
  size_t o = 0;
  auto take = [&](size_t bytes) -> void* {
    void* p = ws + o;
    o += (bytes + 255) & ~(size_t)255;
    return p;
  };
  const int NB = (n + 255) / 256;   // scan blocks (196)
  int*   cnt     = (int*)take((size_t)n * 4);
  int*   row_ptr = (int*)take((size_t)(n + 1) * 4);
  int*   nxt     = (int*)take((size_t)n * 4);
  float* dinv    = (float*)take((size_t)n * 4);
  int*   bsum    = (int*)take((size_t)NB * 4);
  int*   col     = (int*)take((size_t)E * 4);
  float* wcsr    = (float*)take((size_t)E * 4);
  float* ax      = (float*)take((size_t)n * 64 * 4);
  float* y1      = (float*)take((size_t)n * 128 * 4);
  float* h2      = ax;  // ax dead after gemm1; reuse

  hipMemsetAsync(cnt, 0, (size_t)n * 4, stream);

  int eb = (E + 255) / 256;
  count_kernel<<<eb, 256, 0, stream>>>(edst, cnt, E);
  scan_up<<<NB, 256, 0, stream>>>(cnt, row_ptr, bsum, n);
  scan_mid<<<1, 256, 0, stream>>>(bsum, NB);
  scan_down<<<NB, 256, 0, stream>>>(row_ptr, bsum, nxt, cnt, dinv, n, E);
  fill_kernel<<<eb, 256, 0, stream>>>(esrc, edst, dinv, nxt, col, wcsr, E);

  aggx_kernel<<<(n + 3) / 4, 256, 0, stream>>>(x, dinv, row_ptr, col, wcsr, ax, n);
  gemm1_kernel<<<512, 256, 0, stream>>>(ax, W1, b1, y1, n);
  gemm2_kernel<<<512, 256, 0, stream>>>(y1, W2, h2, n);
  agg2_kernel<<<(n + 3) / 4, 256, 0, stream>>>(h2, dinv, row_ptr, col, wcsr, b2, x,
                                               (float*)d_out, n);
}

// Round 4
// 229.975 us; speedup vs baseline: 2.3980x; 1.5496x over previous
//
#include <hip/hip_runtime.h>

#define NEG 0.01f

// ---------------- CSR build ----------------

__global__ void count_kernel(const int* __restrict__ dst, int* __restrict__ cnt, int E) {
  int e = blockIdx.x * blockDim.x + threadIdx.x;
  if (e < E) atomicAdd(&cnt[dst[e]], 1);
}

__global__ __launch_bounds__(256) void scan_up(const int* __restrict__ cnt,
                                               int* __restrict__ row_ptr,
                                               int* __restrict__ bsum, int n) {
  __shared__ int s[256];
  int t = threadIdx.x;
  int i = blockIdx.x * 256 + t;
  int v = (i < n) ? cnt[i] : 0;
  s[t] = v;
  __syncthreads();
  for (int off = 1; off < 256; off <<= 1) {
    int u = (t >= off) ? s[t - off] : 0;
    __syncthreads();
    s[t] += u;
    __syncthreads();
  }
  if (i < n) row_ptr[i] = s[t] - v;
  if (t == 255) bsum[blockIdx.x] = s[255];
}

__global__ __launch_bounds__(256) void scan_mid(int* __restrict__ bsum, int B) {
  __shared__ int s[256];
  int t = threadIdx.x;
  int chunk = (B + 255) >> 8;
  int st = t * chunk, en = min(st + chunk, B);
  int sum = 0;
  for (int i = st; i < en; ++i) sum += bsum[i];
  s[t] = sum;
  __syncthreads();
  for (int off = 1; off < 256; off <<= 1) {
    int u = (t >= off) ? s[t - off] : 0;
    __syncthreads();
    s[t] += u;
    __syncthreads();
  }
  int run = s[t] - sum;
  for (int i = st; i < en; ++i) {
    int c = bsum[i];
    bsum[i] = run;
    run += c;
  }
}

__global__ __launch_bounds__(256) void scan_down(int* __restrict__ row_ptr,
                                                 const int* __restrict__ bsum,
                                                 int* __restrict__ nxt,
                                                 const int* __restrict__ cnt,
                                                 float* __restrict__ dinv, int n, int E) {
  int i = blockIdx.x * 256 + threadIdx.x;
  if (i < n) {
    int r = row_ptr[i] + bsum[blockIdx.x];
    row_ptr[i] = r;
    nxt[i] = r;
    dinv[i] = rsqrtf((float)cnt[i] + 1.0f);  // +1 self-loop
  }
  if (i == 0) row_ptr[n] = E;
}

// packed edge record: .x = col (src node), .y = bits of weight
__global__ void fill_kernel(const int* __restrict__ src, const int* __restrict__ dst,
                            const float* __restrict__ dinv, int* __restrict__ nxt,
                            uint2* __restrict__ ew, int E) {
  int e = blockIdx.x * blockDim.x + threadIdx.x;
  if (e < E) {
    int d = dst[e], s = src[e];
    int pos = atomicAdd(&nxt[d], 1);
    uint2 rec;
    rec.x = (unsigned)s;
    rec.y = __float_as_uint(dinv[s] * dinv[d]);
    ew[pos] = rec;
  }
}

// ---------------- Aggregation: 1 wave/node, 16 lanes x float4 per row, 4 edges/instr ----------------
// acc layout: lane (g,fl) g=lane>>4 edge-slot, fl=lane&15 feature-quad.

__global__ __launch_bounds__(256) void aggx_kernel(const float* __restrict__ x,
                                                   const float* __restrict__ dinv,
                                                   const int* __restrict__ row_ptr,
                                                   const uint2* __restrict__ ew,
                                                   float* __restrict__ ax, int n) {
  int lane = threadIdx.x & 63;
  int g = lane >> 4, fl = lane & 15;
  int i = blockIdx.x * 4 + (threadIdx.x >> 6);
  if (i >= n) return;
  int e0 = row_ptr[i], e1 = row_ptr[i + 1];
  float4 acc = make_float4(0.f, 0.f, 0.f, 0.f);
  float4 acc2 = make_float4(0.f, 0.f, 0.f, 0.f);
  int e = e0;
  for (; e + 8 <= e1; e += 8) {
    uint2 p0 = ew[e + g];
    uint2 p1 = ew[e + 4 + g];
    float w0 = __uint_as_float(p0.y);
    float w1 = __uint_as_float(p1.y);
    float4 v0 = *(const float4*)&x[(size_t)p0.x * 64 + fl * 4];
    float4 v1 = *(const float4*)&x[(size_t)p1.x * 64 + fl * 4];
    acc.x = fmaf(w0, v0.x, acc.x);
    acc.y = fmaf(w0, v0.y, acc.y);
    acc.z = fmaf(w0, v0.z, acc.z);
    acc.w = fmaf(w0, v0.w, acc.w);
    acc2.x = fmaf(w1, v1.x, acc2.x);
    acc2.y = fmaf(w1, v1.y, acc2.y);
    acc2.z = fmaf(w1, v1.z, acc2.z);
    acc2.w = fmaf(w1, v1.w, acc2.w);
  }
  for (; e < e1; e += 4) {
    int eg = e + g;
    bool valid = eg < e1;
    uint2 p = ew[valid ? eg : e];
    float w = valid ? __uint_as_float(p.y) : 0.f;
    float4 v = *(const float4*)&x[(size_t)p.x * 64 + fl * 4];
    acc.x = fmaf(w, v.x, acc.x);
    acc.y = fmaf(w, v.y, acc.y);
    acc.z = fmaf(w, v.z, acc.z);
    acc.w = fmaf(w, v.w, acc.w);
  }
  acc.x += acc2.x; acc.y += acc2.y; acc.z += acc2.z; acc.w += acc2.w;
  acc.x += __shfl_xor(acc.x, 16); acc.y += __shfl_xor(acc.y, 16);
  acc.z += __shfl_xor(acc.z, 16); acc.w += __shfl_xor(acc.w, 16);
  acc.x += __shfl_xor(acc.x, 32); acc.y += __shfl_xor(acc.y, 32);
  acc.z += __shfl_xor(acc.z, 32); acc.w += __shfl_xor(acc.w, 32);
  if (g == 0) {
    float di = dinv[i];
    float d2 = di * di;
    float4 self = *(const float4*)&x[(size_t)i * 64 + fl * 4];
    float4 o;
    o.x = fmaf(d2, self.x, acc.x);
    o.y = fmaf(d2, self.y, acc.y);
    o.z = fmaf(d2, self.z, acc.z);
    o.w = fmaf(d2, self.w, acc.w);
    *(float4*)&ax[(size_t)i * 64 + fl * 4] = o;
  }
}

__global__ __launch_bounds__(256) void agg2_kernel(const float* __restrict__ h2,
                                                   const float* __restrict__ dinv,
                                                   const int* __restrict__ row_ptr,
                                                   const uint2* __restrict__ ew,
                                                   const float* __restrict__ b,
                                                   const float* __restrict__ x,
                                                   float* __restrict__ out, int n) {
  int lane = threadIdx.x & 63;
  int g = lane >> 4, fl = lane & 15;
  int i = blockIdx.x * 4 + (threadIdx.x >> 6);
  if (i >= n) return;
  int e0 = row_ptr[i], e1 = row_ptr[i + 1];
  float4 acc = make_float4(0.f, 0.f, 0.f, 0.f);
  float4 acc2 = make_float4(0.f, 0.f, 0.f, 0.f);
  int e = e0;
  for (; e + 8 <= e1; e += 8) {
    uint2 p0 = ew[e + g];
    uint2 p1 = ew[e + 4 + g];
    float w0 = __uint_as_float(p0.y);
    float w1 = __uint_as_float(p1.y);
    float4 v0 = *(const float4*)&h2[(size_t)p0.x * 64 + fl * 4];
    float4 v1 = *(const float4*)&h2[(size_t)p1.x * 64 + fl * 4];
    acc.x = fmaf(w0, v0.x, acc.x);
    acc.y = fmaf(w0, v0.y, acc.y);
    acc.z = fmaf(w0, v0.z, acc.z);
    acc.w = fmaf(w0, v0.w, acc.w);
    acc2.x = fmaf(w1, v1.x, acc2.x);
    acc2.y = fmaf(w1, v1.y, acc2.y);
    acc2.z = fmaf(w1, v1.z, acc2.z);
    acc2.w = fmaf(w1, v1.w, acc2.w);
  }
  for (; e < e1; e += 4) {
    int eg = e + g;
    bool valid = eg < e1;
    uint2 p = ew[valid ? eg : e];
    float w = valid ? __uint_as_float(p.y) : 0.f;
    float4 v = *(const float4*)&h2[(size_t)p.x * 64 + fl * 4];
    acc.x = fmaf(w, v.x, acc.x);
    acc.y = fmaf(w, v.y, acc.y);
    acc.z = fmaf(w, v.z, acc.z);
    acc.w = fmaf(w, v.w, acc.w);
  }
  acc.x += acc2.x; acc.y += acc2.y; acc.z += acc2.z; acc.w += acc2.w;
  acc.x += __shfl_xor(acc.x, 16); acc.y += __shfl_xor(acc.y, 16);
  acc.z += __shfl_xor(acc.z, 16); acc.w += __shfl_xor(acc.w, 16);
  acc.x += __shfl_xor(acc.x, 32); acc.y += __shfl_xor(acc.y, 32);
  acc.z += __shfl_xor(acc.z, 32); acc.w += __shfl_xor(acc.w, 32);
  if (g == 0) {
    float di = dinv[i];
    float d2 = di * di;
    float4 self = *(const float4*)&h2[(size_t)i * 64 + fl * 4];
    float4 xr = *(const float4*)&x[(size_t)i * 64 + fl * 4];
    float4 bb = *(const float4*)&b[fl * 4];
    float4 o;
    o.x = xr.x + bb.x + fmaf(d2, self.x, acc.x);
    o.y = xr.y + bb.y + fmaf(d2, self.y, acc.y);
    o.z = xr.z + bb.z + fmaf(d2, self.z, acc.z);
    o.w = xr.w + bb.w + fmaf(d2, self.w, acc.w);
    *(float4*)&out[(size_t)i * 64 + fl * 4] = o;
  }
}

// ---------------- GEMMs: W column register-cached, sx broadcast via LDS ----------------

// y1[n,128] = leaky(ax[n,64] @ W1[64,128] + b1); 2 nodes/iter, 1 out/thread
__global__ __launch_bounds__(256) void gemm1_kernel(const float* __restrict__ ax,
                                                    const float* __restrict__ W,
                                                    const float* __restrict__ b,
                                                    float* __restrict__ y1, int n) {
  __shared__ float sx[2][64];
  int t = threadIdx.x;
  int j = t & 127, local = t >> 7;
  float Wreg[64];
#pragma unroll
  for (int k = 0; k < 64; ++k) Wreg[k] = W[k * 128 + j];  // coalesced; reused 49x
  float bj = b[j];
  int npairs = (n + 1) >> 1;
  for (int p = blockIdx.x; p < npairs; p += gridDim.x) {
    int node0 = p << 1;
    __syncthreads();
    if (t < 128) {
      int node = node0 + (t >> 6);
      sx[t >> 6][t & 63] = (node < n) ? ax[(size_t)node * 64 + (t & 63)] : 0.f;
    }
    __syncthreads();
    int node = node0 + local;
    if (node < n) {
      float acc = 0.f;
      const float4* sx4 = (const float4*)sx[local];
#pragma unroll
      for (int k4 = 0; k4 < 16; ++k4) {
        float4 a = sx4[k4];
        acc = fmaf(a.x, Wreg[k4 * 4 + 0], acc);
        acc = fmaf(a.y, Wreg[k4 * 4 + 1], acc);
        acc = fmaf(a.z, Wreg[k4 * 4 + 2], acc);
        acc = fmaf(a.w, Wreg[k4 * 4 + 3], acc);
      }
      float s = acc + bj;
      y1[(size_t)node * 128 + j] = (s >= 0.f) ? s : NEG * s;
    }
  }
}

// h2[n,64] = y1[n,128] @ W2[128,64]; 4 nodes/iter, 1 out/thread
__global__ __launch_bounds__(256) void gemm2_kernel(const float* __restrict__ y,
                                                    const float* __restrict__ W,
                                                    float* __restrict__ h2, int n) {
  __shared__ float sy[4][128];
  int t = threadIdx.x;
  int j = t & 63, local = t >> 6;
  float Wreg[128];
#pragma unroll
  for (int k = 0; k < 128; ++k) Wreg[k] = W[k * 64 + j];
  int nquads = (n + 3) >> 2;
  for (int q = blockIdx.x; q < nquads; q += gridDim.x) {
    int node0 = q << 2;
    __syncthreads();
    if (t < 128) {
      int nl = t >> 5;            // node slot 0..3
      int k4 = (t & 31) * 4;      // feature quad
      int node = node0 + nl;
      float4 v = (node < n) ? *(const float4*)&y[(size_t)node * 128 + k4]
                            : make_float4(0.f, 0.f, 0.f, 0.f);
      *(float4*)&sy[nl][k4] = v;
    }
    __syncthreads();
    int node = node0 + local;
    if (node < n) {
      float acc = 0.f;
      const float4* sy4 = (const float4*)sy[local];
#pragma unroll
      for (int k4 = 0; k4 < 32; ++k4) {
        float4 a = sy4[k4];
        acc = fmaf(a.x, Wreg[k4 * 4 + 0], acc);
        acc = fmaf(a.y, Wreg[k4 * 4 + 1], acc);
        acc = fmaf(a.z, Wreg[k4 * 4 + 2], acc);
        acc = fmaf(a.w, Wreg[k4 * 4 + 3], acc);
      }
      h2[(size_t)node * 64 + j] = acc;
    }
  }
}

// ---------------- launch ----------------

extern "C" void kernel_launch(void* const* d_in, const int* in_sizes, int n_in,
                              void* d_out, int out_size, void* d_ws, size_t ws_size,
                              hipStream_t stream) {
  const int n = in_sizes[0] / 64;   // 50000
  const int E = in_sizes[5] / 2;    // 800000

  const float* x  = (const float*)d_in[0];
  const float* W1 = (const float*)d_in[1];
  const float* b1 = (const float*)d_in[2];
  const float* W2 = (const float*)d_in[3];
  const float* b2 = (const float*)d_in[4];
  const int* edge = (const int*)d_in[5];
  const int* esrc = edge;       // edge_index[0]
  const int* edst = edge + E;   // edge_index[1]

  char* ws = (char*)d_ws;
  size_t o = 0;
  auto take = [&](size_t bytes) -> void* {
    void* p = ws + o;
    o += (bytes + 255) & ~(size_t)255;
    return p;
  };
  const int NB = (n + 255) / 256;
  int*   cnt     = (int*)take((size_t)n * 4);
  int*   row_ptr = (int*)take((size_t)(n + 1) * 4);
  int*   nxt     = (int*)take((size_t)n * 4);
  float* dinv    = (float*)take((size_t)n * 4);
  int*   bsum    = (int*)take((size_t)NB * 4);
  uint2* ew      = (uint2*)take((size_t)E * 8);
  float* ax      = (float*)take((size_t)n * 64 * 4);
  float* y1      = (float*)take((size_t)n * 128 * 4);
  float* h2      = ax;  // ax dead after gemm1; reuse

  hipMemsetAsync(cnt, 0, (size_t)n * 4, stream);

  int eb = (E + 255) / 256;
  count_kernel<<<eb, 256, 0, stream>>>(edst, cnt, E);
  scan_up<<<NB, 256, 0, stream>>>(cnt, row_ptr, bsum, n);
  scan_mid<<<1, 256, 0, stream>>>(bsum, NB);
  scan_down<<<NB, 256, 0, stream>>>(row_ptr, bsum, nxt, cnt, dinv, n, E);
  fill_kernel<<<eb, 256, 0, stream>>>(esrc, edst, dinv, nxt, ew, E);

  aggx_kernel<<<(n + 3) / 4, 256, 0, stream>>>(x, dinv, row_ptr, ew, ax, n);
  gemm1_kernel<<<512, 256, 0, stream>>>(ax, W1, b1, y1, n);
  gemm2_kernel<<<512, 256, 0, stream>>>(y1, W2, h2, n);
  agg2_kernel<<<(n + 3) / 4, 256, 0, stream>>>(h2, dinv, row_ptr, ew, b2, x,
                                               (float*)d_out, n);
}

// Round 5
// 168.047 us; speedup vs baseline: 3.2817x; 1.3685x over previous
//
#include <hip/hip_runtime.h>

#define NEG 0.01f
#define NBUCK_MAX 512   // buckets of 128 nodes; 50000/128 -> 391 used
#define CHUNK 4096      // edges per partition block
#define CAP 4096        // LDS edge capacity in finalize (avg bucket ~2046)

typedef unsigned int uint;
typedef unsigned short ush;

__device__ __forceinline__ float bf2f(ush u) { return __uint_as_float(((uint)u) << 16); }
__device__ __forceinline__ ush f2bf(float f) {
  uint u = __float_as_uint(f);
  u += 0x7FFFu + ((u >> 16) & 1u);   // RNE
  return (ush)(u >> 16);
}

// ---------------- P0: bucket histogram (LDS-staged) ----------------

__global__ __launch_bounds__(256) void bucket_count(const int* __restrict__ dst,
                                                    int* __restrict__ bcnt, int E) {
  __shared__ int h[NBUCK_MAX];
  int t = threadIdx.x;
  for (int b = t; b < NBUCK_MAX; b += 256) h[b] = 0;
  __syncthreads();
  int base = blockIdx.x * CHUNK;
#pragma unroll
  for (int c = 0; c < CHUNK / 256; ++c) {
    int e = base + c * 256 + t;
    if (e < E) atomicAdd(&h[dst[e] >> 7], 1);
  }
  __syncthreads();
  for (int b = t; b < NBUCK_MAX; b += 256)
    if (h[b]) atomicAdd(&bcnt[b], h[b]);
}

// ---------------- P1: scan 512 bucket counts (1 block) ----------------

__global__ __launch_bounds__(256) void bucket_scan(const int* __restrict__ bcnt,
                                                   int* __restrict__ bbase,
                                                   int* __restrict__ bnext, int E) {
  __shared__ int sc[256];
  int t = threadIdx.x;
  int s0 = bcnt[2 * t], s1 = bcnt[2 * t + 1];
  int p = s0 + s1;
  sc[t] = p;
  __syncthreads();
  for (int off = 1; off < 256; off <<= 1) {
    int v = (t >= off) ? sc[t - off] : 0;
    __syncthreads();
    sc[t] += v;
    __syncthreads();
  }
  int ex = sc[t] - p;
  bbase[2 * t] = ex;
  bbase[2 * t + 1] = ex + s0;
  bnext[2 * t] = ex;
  bnext[2 * t + 1] = ex + s0;
  if (t == 255) bbase[512] = E;
}

// ---------------- P2: partition edges into bucket-grouped tmp (coalesced writes) ----------------

__global__ __launch_bounds__(256) void partition_kernel(const int* __restrict__ src,
                                                        const int* __restrict__ dst,
                                                        int* __restrict__ bnext,
                                                        uint2* __restrict__ tmp, int E) {
  __shared__ int hcnt[NBUCK_MAX];
  __shared__ int hbase[NBUCK_MAX];
  __shared__ int gbase[NBUCK_MAX];
  __shared__ int sc[256];
  __shared__ uint lsrc[CHUNK];
  __shared__ uint ldst[CHUNK];
  int t = threadIdx.x;
  for (int b = t; b < NBUCK_MAX; b += 256) hcnt[b] = 0;
  __syncthreads();
  int base = blockIdx.x * CHUNK;
  uint es[CHUNK / 256], ed[CHUNK / 256];
  int slot[CHUNK / 256];
#pragma unroll
  for (int c = 0; c < CHUNK / 256; ++c) {
    int e = base + c * 256 + t;
    slot[c] = -1;
    if (e < E) {
      es[c] = (uint)src[e];
      ed[c] = (uint)dst[e];
      slot[c] = atomicAdd(&hcnt[ed[c] >> 7], 1);
    }
  }
  __syncthreads();
  // exclusive scan of hcnt[512], pair per thread
  int s0 = hcnt[2 * t], s1 = hcnt[2 * t + 1];
  int p = s0 + s1;
  sc[t] = p;
  __syncthreads();
  for (int off = 1; off < 256; off <<= 1) {
    int v = (t >= off) ? sc[t - off] : 0;
    __syncthreads();
    sc[t] += v;
    __syncthreads();
  }
  int ex = sc[t] - p;
  hbase[2 * t] = ex;
  hbase[2 * t + 1] = ex + s0;
  __syncthreads();
  // scatter into LDS, bucket-sorted
#pragma unroll
  for (int c = 0; c < CHUNK / 256; ++c) {
    if (slot[c] >= 0) {
      int pidx = hbase[ed[c] >> 7] + slot[c];
      lsrc[pidx] = es[c];
      ldst[pidx] = ed[c];
    }
  }
  // reserve contiguous global regions per bucket
  for (int b = t; b < NBUCK_MAX; b += 256)
    if (hcnt[b]) gbase[b] = atomicAdd(&bnext[b], hcnt[b]);
  __syncthreads();
  // linear (coalesced) write-out
  int m = min(CHUNK, E - base);
  for (int idx = t; idx < m; idx += 256) {
    uint s = lsrc[idx], d = ldst[idx];
    int b = (int)(d >> 7);
    tmp[gbase[b] + (idx - hbase[b])] = make_uint2(s, d);
  }
}

// ---------------- P4: per-bucket CSR finalize: row_ptr, dinv, sorted col ----------------

__global__ __launch_bounds__(256) void csr_finalize(const uint2* __restrict__ tmp,
                                                    const int* __restrict__ bbase,
                                                    int* __restrict__ row_ptr,
                                                    float* __restrict__ dinv,
                                                    int* __restrict__ col, int n, int E) {
  __shared__ int lcnt[128];
  __shared__ int lnxt[128];
  __shared__ int lsc[128];
  __shared__ uint lcol[CAP];
  int b = blockIdx.x;
  int t = threadIdx.x;
  int node0 = b << 7;
  int rp0 = bbase[b], rp1 = bbase[b + 1];
  int m = rp1 - rp0;
  if (t < 128) lcnt[t] = 0;
  __syncthreads();
  for (int idx = t; idx < m; idx += 256)
    atomicAdd(&lcnt[(int)tmp[rp0 + idx].y - node0], 1);
  __syncthreads();
  if (t < 128) lsc[t] = lcnt[t];
  __syncthreads();
  for (int off = 1; off < 128; off <<= 1) {
    int v = 0;
    if (t < 128 && t >= off) v = lsc[t - off];
    __syncthreads();
    if (t < 128) lsc[t] += v;
    __syncthreads();
  }
  if (t < 128) {
    int node = node0 + t;
    int ex = lsc[t] - lcnt[t];
    if (node < n) {
      row_ptr[node] = rp0 + ex;
      dinv[node] = rsqrtf((float)lcnt[t] + 1.0f);  // +1 self-loop
    }
    lnxt[t] = ex;
  }
  if (b == (int)gridDim.x - 1 && t == 0) row_ptr[n] = E;
  __syncthreads();
  if (m <= CAP) {
    for (int idx = t; idx < m; idx += 256) {
      uint2 r = tmp[rp0 + idx];
      int p = atomicAdd(&lnxt[(int)r.y - node0], 1);
      lcol[p] = r.x;
    }
    __syncthreads();
    for (int idx = t; idx < m; idx += 256) col[rp0 + idx] = (int)lcol[idx];
  } else {  // overflow fallback (statistically unreachable)
    for (int idx = t; idx < m; idx += 256) {
      uint2 r = tmp[rp0 + idx];
      int p = atomicAdd(&lnxt[(int)r.y - node0], 1);
      col[rp0 + p] = (int)r.x;
    }
  }
}

// ---------------- xs = bf16(dinv ⊙ x) ----------------

__global__ __launch_bounds__(256) void xscale_kernel(const float* __restrict__ x,
                                                     const float* __restrict__ dinv,
                                                     ush* __restrict__ xs, int total4) {
  int idx = blockIdx.x * 256 + threadIdx.x;  // one float4 per thread
  if (idx >= total4) return;
  float di = dinv[idx >> 4];  // 16 quads per 64-feat row
  float4 v = ((const float4*)x)[idx];
  ushort4 o;
  o.x = f2bf(v.x * di);
  o.y = f2bf(v.y * di);
  o.z = f2bf(v.z * di);
  o.w = f2bf(v.w * di);
  ((ushort4*)xs)[idx] = o;
}

// ---------------- Aggregation: 1 wave/node, 16 lanes x bf16x4, 4 edges/instr ----------------
// ax[i,:] = dinv[i] * ( sum_{s in N(i)} xs[s,:] + xs[i,:] )   (weights folded into xs)

__global__ __launch_bounds__(256) void aggx_kernel(const ush* __restrict__ xs,
                                                   const float* __restrict__ dinv,
                                                   const int* __restrict__ row_ptr,
                                                   const int* __restrict__ col,
                                                   float* __restrict__ ax, int n) {
  int lane = threadIdx.x & 63;
  int g = lane >> 4, fl = lane & 15;
  int i = blockIdx.x * 4 + (threadIdx.x >> 6);
  if (i >= n) return;
  int e0 = row_ptr[i], e1 = row_ptr[i + 1];
  float4 acc = make_float4(0.f, 0.f, 0.f, 0.f);
  float4 acc2 = make_float4(0.f, 0.f, 0.f, 0.f);
  int e = e0;
  for (; e + 8 <= e1; e += 8) {
    int c0 = col[e + g], c1 = col[e + 4 + g];
    ushort4 u0 = *(const ushort4*)&xs[(size_t)c0 * 64 + fl * 4];
    ushort4 u1 = *(const ushort4*)&xs[(size_t)c1 * 64 + fl * 4];
    acc.x += bf2f(u0.x);  acc.y += bf2f(u0.y);  acc.z += bf2f(u0.z);  acc.w += bf2f(u0.w);
    acc2.x += bf2f(u1.x); acc2.y += bf2f(u1.y); acc2.z += bf2f(u1.z); acc2.w += bf2f(u1.w);
  }
  for (; e < e1; e += 4) {
    int eg = e + g;
    bool valid = eg < e1;
    int c = col[valid ? eg : e];
    ushort4 u = *(const ushort4*)&xs[(size_t)c * 64 + fl * 4];
    float msk = valid ? 1.f : 0.f;
    acc.x = fmaf(msk, bf2f(u.x), acc.x);
    acc.y = fmaf(msk, bf2f(u.y), acc.y);
    acc.z = fmaf(msk, bf2f(u.z), acc.z);
    acc.w = fmaf(msk, bf2f(u.w), acc.w);
  }
  acc.x += acc2.x; acc.y += acc2.y; acc.z += acc2.z; acc.w += acc2.w;
  acc.x += __shfl_xor(acc.x, 16); acc.y += __shfl_xor(acc.y, 16);
  acc.z += __shfl_xor(acc.z, 16); acc.w += __shfl_xor(acc.w, 16);
  acc.x += __shfl_xor(acc.x, 32); acc.y += __shfl_xor(acc.y, 32);
  acc.z += __shfl_xor(acc.z, 32); acc.w += __shfl_xor(acc.w, 32);
  if (g == 0) {
    ushort4 us = *(const ushort4*)&xs[(size_t)i * 64 + fl * 4];
    float di = dinv[i];
    float4 o;
    o.x = di * (acc.x + bf2f(us.x));
    o.y = di * (acc.y + bf2f(us.y));
    o.z = di * (acc.z + bf2f(us.z));
    o.w = di * (acc.w + bf2f(us.w));
    *(float4*)&ax[(size_t)i * 64 + fl * 4] = o;
  }
}

// out[i,:] = x[i,:] + b2 + dinv[i] * ( sum h2s[s,:] + h2s[i,:] )
__global__ __launch_bounds__(256) void agg2_kernel(const ush* __restrict__ h2s,
                                                   const float* __restrict__ dinv,
                                                   const int* __restrict__ row_ptr,
                                                   const int* __restrict__ col,
                                                   const float* __restrict__ b,
                                                   const float* __restrict__ x,
                                                   float* __restrict__ out, int n) {
  int lane = threadIdx.x & 63;
  int g = lane >> 4, fl = lane & 15;
  int i = blockIdx.x * 4 + (threadIdx.x >> 6);
  if (i >= n) return;
  int e0 = row_ptr[i], e1 = row_ptr[i + 1];
  float4 acc = make_float4(0.f, 0.f, 0.f, 0.f);
  float4 acc2 = make_float4(0.f, 0.f, 0.f, 0.f);
  int e = e0;
  for (; e + 8 <= e1; e += 8) {
    int c0 = col[e + g], c1 = col[e + 4 + g];
    ushort4 u0 = *(const ushort4*)&h2s[(size_t)c0 * 64 + fl * 4];
    ushort4 u1 = *(const ushort4*)&h2s[(size_t)c1 * 64 + fl * 4];
    acc.x += bf2f(u0.x);  acc.y += bf2f(u0.y);  acc.z += bf2f(u0.z);  acc.w += bf2f(u0.w);
    acc2.x += bf2f(u1.x); acc2.y += bf2f(u1.y); acc2.z += bf2f(u1.z); acc2.w += bf2f(u1.w);
  }
  for (; e < e1; e += 4) {
    int eg = e + g;
    bool valid = eg < e1;
    int c = col[valid ? eg : e];
    ushort4 u = *(const ushort4*)&h2s[(size_t)c * 64 + fl * 4];
    float msk = valid ? 1.f : 0.f;
    acc.x = fmaf(msk, bf2f(u.x), acc.x);
    acc.y = fmaf(msk, bf2f(u.y), acc.y);
    acc.z = fmaf(msk, bf2f(u.z), acc.z);
    acc.w = fmaf(msk, bf2f(u.w), acc.w);
  }
  acc.x += acc2.x; acc.y += acc2.y; acc.z += acc2.z; acc.w += acc2.w;
  acc.x += __shfl_xor(acc.x, 16); acc.y += __shfl_xor(acc.y, 16);
  acc.z += __shfl_xor(acc.z, 16); acc.w += __shfl_xor(acc.w, 16);
  acc.x += __shfl_xor(acc.x, 32); acc.y += __shfl_xor(acc.y, 32);
  acc.z += __shfl_xor(acc.z, 32); acc.w += __shfl_xor(acc.w, 32);
  if (g == 0) {
    ushort4 us = *(const ushort4*)&h2s[(size_t)i * 64 + fl * 4];
    float di = dinv[i];
    float4 xr = *(const float4*)&x[(size_t)i * 64 + fl * 4];
    float4 bb = *(const float4*)&b[fl * 4];
    float4 o;
    o.x = xr.x + bb.x + di * (acc.x + bf2f(us.x));
    o.y = xr.y + bb.y + di * (acc.y + bf2f(us.y));
    o.z = xr.z + bb.z + di * (acc.z + bf2f(us.z));
    o.w = xr.w + bb.w + di * (acc.w + bf2f(us.w));
    *(float4*)&out[(size_t)i * 64 + fl * 4] = o;
  }
}

// ---------------- GEMMs: W column register-cached, x broadcast via LDS ----------------

// y1[n,128] = leaky(ax[n,64] @ W1[64,128] + b1); 2 nodes/iter, 1 out/thread
__global__ __launch_bounds__(256) void gemm1_kernel(const float* __restrict__ ax,
                                                    const float* __restrict__ W,
                                                    const float* __restrict__ b,
                                                    float* __restrict__ y1, int n) {
  __shared__ float sx[2][64];
  int t = threadIdx.x;
  int j = t & 127, local = t >> 7;
  float Wreg[64];
#pragma unroll
  for (int k = 0; k < 64; ++k) Wreg[k] = W[k * 128 + j];
  float bj = b[j];
  int npairs = (n + 1) >> 1;
  for (int p = blockIdx.x; p < npairs; p += gridDim.x) {
    int node0 = p << 1;
    __syncthreads();
    if (t < 128) {
      int node = node0 + (t >> 6);
      sx[t >> 6][t & 63] = (node < n) ? ax[(size_t)node * 64 + (t & 63)] : 0.f;
    }
    __syncthreads();
    int node = node0 + local;
    if (node < n) {
      float acc = 0.f;
      const float4* sx4 = (const float4*)sx[local];
#pragma unroll
      for (int k4 = 0; k4 < 16; ++k4) {
        float4 a = sx4[k4];
        acc = fmaf(a.x, Wreg[k4 * 4 + 0], acc);
        acc = fmaf(a.y, Wreg[k4 * 4 + 1], acc);
        acc = fmaf(a.z, Wreg[k4 * 4 + 2], acc);
        acc = fmaf(a.w, Wreg[k4 * 4 + 3], acc);
      }
      float s = acc + bj;
      y1[(size_t)node * 128 + j] = (s >= 0.f) ? s : NEG * s;
    }
  }
}

// h2s[n,64] = bf16( dinv ⊙ (y1[n,128] @ W2[128,64]) ); 4 nodes/iter, 1 out/thread
__global__ __launch_bounds__(256) void gemm2_kernel(const float* __restrict__ y,
                                                    const float* __restrict__ W,
                                                    const float* __restrict__ dinv,
                                                    ush* __restrict__ h2s, int n) {
  __shared__ float sy[4][128];
  int t = threadIdx.x;
  int j = t & 63, local = t >> 6;
  float Wreg[128];
#pragma unroll
  for (int k = 0; k < 128; ++k) Wreg[k] = W[k * 64 + j];
  int nquads = (n + 3) >> 2;
  for (int q = blockIdx.x; q < nquads; q += gridDim.x) {
    int node0 = q << 2;
    __syncthreads();
    if (t < 128) {
      int nl = t >> 5;
      int k4 = (t & 31) * 4;
      int node = node0 + nl;
      float4 v = (node < n) ? *(const float4*)&y[(size_t)node * 128 + k4]
                            : make_float4(0.f, 0.f, 0.f, 0.f);
      *(float4*)&sy[nl][k4] = v;
    }
    __syncthreads();
    int node = node0 + local;
    if (node < n) {
      float acc = 0.f;
      const float4* sy4 = (const float4*)sy[local];
#pragma unroll
      for (int k4 = 0; k4 < 32; ++k4) {
        float4 a = sy4[k4];
        acc = fmaf(a.x, Wreg[k4 * 4 + 0], acc);
        acc = fmaf(a.y, Wreg[k4 * 4 + 1], acc);
        acc = fmaf(a.z, Wreg[k4 * 4 + 2], acc);
        acc = fmaf(a.w, Wreg[k4 * 4 + 3], acc);
      }
      h2s[(size_t)node * 64 + j] = f2bf(acc * dinv[node]);
    }
  }
}

// ---------------- launch ----------------

extern "C" void kernel_launch(void* const* d_in, const int* in_sizes, int n_in,
                              void* d_out, int out_size, void* d_ws, size_t ws_size,
                              hipStream_t stream) {
  const int n = in_sizes[0] / 64;   // 50000
  const int E = in_sizes[5] / 2;    // 800000

  const float* x  = (const float*)d_in[0];
  const float* W1 = (const float*)d_in[1];
  const float* b1 = (const float*)d_in[2];
  const float* W2 = (const float*)d_in[3];
  const float* b2 = (const float*)d_in[4];
  const int* edge = (const int*)d_in[5];
  const int* esrc = edge;       // edge_index[0]
  const int* edst = edge + E;   // edge_index[1]

  char* ws = (char*)d_ws;
  size_t o = 0;
  auto take = [&](size_t bytes) -> void* {
    void* p = ws + o;
    o += (bytes + 255) & ~(size_t)255;
    return p;
  };
  const int NBUCK = (n + 127) >> 7;  // 391
  int*   bcnt    = (int*)take(512 * 4);
  int*   bbase   = (int*)take(513 * 4);
  int*   bnext   = (int*)take(512 * 4);
  int*   row_ptr = (int*)take((size_t)(n + 1) * 4);
  float* dinv    = (float*)take((size_t)n * 4);
  uint2* tmp     = (uint2*)take((size_t)E * 8);
  int*   col     = (int*)take((size_t)E * 4);
  ush*   xs      = (ush*)take((size_t)n * 64 * 2);
  float* ax      = (float*)take((size_t)n * 64 * 4);
  float* y1      = (float*)take((size_t)n * 128 * 4);
  ush*   h2s     = xs;  // xs dead after aggx; reuse for scaled layer-2 rows

  hipMemsetAsync(bcnt, 0, 512 * 4, stream);

  int pb = (E + CHUNK - 1) / CHUNK;  // 196
  bucket_count<<<pb, 256, 0, stream>>>(edst, bcnt, E);
  bucket_scan<<<1, 256, 0, stream>>>(bcnt, bbase, bnext, E);
  partition_kernel<<<pb, 256, 0, stream>>>(esrc, edst, bnext, tmp, E);
  csr_finalize<<<NBUCK, 256, 0, stream>>>(tmp, bbase, row_ptr, dinv, col, n, E);

  xscale_kernel<<<(n * 16 + 255) / 256, 256, 0, stream>>>(x, dinv, xs, n * 16);
  aggx_kernel<<<(n + 3) / 4, 256, 0, stream>>>(xs, dinv, row_ptr, col, ax, n);
  gemm1_kernel<<<512, 256, 0, stream>>>(ax, W1, b1, y1, n);
  gemm2_kernel<<<512, 256, 0, stream>>>(y1, W2, dinv, h2s, n);
  agg2_kernel<<<(n + 3) / 4, 256, 0, stream>>>(h2s, dinv, row_ptr, col, b2, x,
                                               (float*)d_out, n);
}